// Round 1
// baseline (166.447 us; speedup 1.0000x reference)
//
#include <hip/hip_runtime.h>
#include <hip/hip_bf16.h>

#define B_     4
#define V_IN   12500
#define V_OUT  50000
#define C_IN   64
#define C_OUT  32
#define SPIRAL 9
#define K_NNZ  3
#define ROWS   (B_ * V_OUT)       // 200000
#define KDIM   (SPIRAL * C_IN)    // 576
#define KSTEPS (KDIM / 32)        // 18 (16x16x32 MFMA)
#define WFRAG_ELEMS (KSTEPS * 2 * 64 * 8)  // 18432 bf16 = 36864 B

#define GROUPS_PER_B (V_OUT / 16) // 3125 16-row groups per batch (k1)
#define G1           2048         // k1 blocks (+1 W-prep); 256 per XCD
#define TILES_PER_B  782          // 781 full 64-row tiles + one 16-row tail (k2)
#define G2           1024         // k2 blocks; 128 per XCD; 4 blocks/CU at ~115 VGPR

typedef __attribute__((ext_vector_type(8))) short short8_t;   // 8 bf16 (4 VGPRs)
typedef __attribute__((ext_vector_type(4))) float floatx4;    // 4 fp32 acc

__device__ __forceinline__ unsigned short f32_to_bf16(float f) {
    unsigned int u = __float_as_uint(f);
    unsigned int r = u + 0x7fffu + ((u >> 16) & 1u);   // round-to-nearest-even
    return (unsigned short)(r >> 16);
}

// Kernel 1 (unchanged): up[b,v,c] = sum_k x[b,up_idx[v,k],c]*up_val[v,k]
// -> bf16 in ws. XCD-swizzled: block i serves batch b=(i&7)>>1 so each XCD
// pair's L2 caches x[b] (3.2 MB < 4 MB) and holds dirty up[b] lines for k2.
// Block G1: rearrange weight (576x32 fp32) into MFMA fragment order (bf16):
//   w_frag[((kstep*2+ntile)*64+lane)*8+j] = W[kstep*32+(lane>>4)*8+j][ntile*16+(lane&15)]
__global__ __launch_bounds__(256) void upsample_kernel(
    const float* __restrict__ x,
    const int* __restrict__ up_idx,
    const float* __restrict__ up_val,
    const float* __restrict__ weight,
    unsigned short* __restrict__ up_bf16,
    unsigned short* __restrict__ w_frag)
{
    int tid = threadIdx.x;
    if (blockIdx.x == G1) {
        for (int idx = tid; idx < WFRAG_ELEMS; idx += 256) {
            int j     = idx & 7;
            int lane  = (idx >> 3) & 63;
            int ntile = (idx >> 9) & 1;
            int kstep = idx >> 10;
            int k = kstep * 32 + (lane >> 4) * 8 + j;
            int n = ntile * 16 + (lane & 15);
            w_frag[idx] = f32_to_bf16(weight[k * C_OUT + n]);
        }
        return;
    }
    int xcd = blockIdx.x & 7;
    int b   = xcd >> 1;                     // batch owned by this XCD pair
    int h   = xcd & 1;
    int j   = blockIdx.x >> 3;              // [0, 256)
    int lane16 = tid & 15;                  // 4 channels each
    int sub    = tid >> 4;                  // row within 16-row group

    const float* xb = x + (size_t)b * V_IN * C_IN;
    unsigned short* upb = up_bf16 + (size_t)b * V_OUT * C_IN;

    for (int gl = h + 2 * j; gl < GROUPS_PER_B; gl += 512) {
        int v = gl * 16 + sub;              // local row within batch b
        const int*   ui = up_idx + v * K_NNZ;
        const float* uv = up_val + v * K_NNZ;
        float a0 = 0.f, a1 = 0.f, a2 = 0.f, a3 = 0.f;
#pragma unroll
        for (int k = 0; k < K_NNZ; k++) {
            int u = ui[k];
            float val = uv[k];
            const float4* xp = (const float4*)(xb + (size_t)u * C_IN) + lane16;
            float4 xv = *xp;
            a0 += val * xv.x; a1 += val * xv.y; a2 += val * xv.z; a3 += val * xv.w;
        }
        ushort4 o;
        o.x = f32_to_bf16(a0); o.y = f32_to_bf16(a1);
        o.z = f32_to_bf16(a2); o.w = f32_to_bf16(a3);
        *((ushort4*)(upb + (size_t)v * C_IN) + lane16) = o;
    }
}

// Kernel 2: y[r,n] = relu( sum_f g[r,f]*W[f,n] + bias[n] ),
// g[r, s*64+c] = up[b, spiral[v,s], c].
// R7 change: W fragments live in LDS (36 KB) instead of 144 VGPRs.
// Frees registers -> __launch_bounds__(256,4): 4 waves/SIMD, 4 blocks/CU
// (LDS 4x36 KB = 144 KB <= 160 KB). Grid doubled to 1024 so 4 blocks/CU
// are resident; ~3 tiles/block. Inner loop: 2 ds_read_b128 + 2 MFMA per
// kstep (lane*16B canonical pattern, conflict-free), gathers unchanged.
__global__ __launch_bounds__(256, 4) void gemm_kernel(
    const unsigned short* __restrict__ up_bf16,
    const int* __restrict__ spiral,
    const unsigned short* __restrict__ w_frag,
    const float* __restrict__ bias,
    float* __restrict__ out)
{
    __shared__ unsigned short w_lds[WFRAG_ELEMS];   // 36864 B

    int tid  = threadIdx.x;
    int wave = tid >> 6;
    int lane = tid & 63;
    int m    = lane & 15;
    int quad = lane >> 4;

    // Stage W fragments into LDS once per block (2304 x 16 B, coalesced).
    {
        short8_t* dst = (short8_t*)w_lds;
        const short8_t* src = (const short8_t*)w_frag;
        for (int i = tid; i < WFRAG_ELEMS / 8; i += 256)
            dst[i] = src[i];
    }
    __syncthreads();

    const short8_t* wl = (const short8_t*)w_lds + lane;  // + f*64 -> byte off f*1024

    int xcd = blockIdx.x & 7;
    int b   = xcd >> 1;
    int h   = xcd & 1;
    int j   = blockIdx.x >> 3;              // [0, 128)

    const unsigned short* upb = up_bf16 + (size_t)b * V_OUT * C_IN;
    float* outb = out + (size_t)b * V_OUT * C_OUT;

    float4 bias0 = ((const float4*)bias)[quad];      // bias[quad*4 .. +3]
    float4 bias1 = ((const float4*)bias)[4 + quad];  // bias[16+quad*4 .. +3]

    for (int tl = h + 2 * j; tl < TILES_PER_B; tl += 256) {
        int vr = tl * 64 + wave * 16 + m;            // local output row in b
        int valid = vr < V_OUT;                      // tail tile: 16 valid rows
        int v = valid ? vr : 0;
        const int* sp = spiral + v * SPIRAL;

        // preload all 18 g-fragments (18 x 16B in flight per lane)
        short8_t g0[SPIRAL], g1[SPIRAL];
#pragma unroll
        for (int s = 0; s < SPIRAL; s++) {
            const unsigned short* rowp = upb + (size_t)sp[s] * C_IN;
            g0[s] = *(const short8_t*)(rowp + quad * 8);
            g1[s] = *(const short8_t*)(rowp + 32 + quad * 8);
        }

        floatx4 acc0 = {0.f, 0.f, 0.f, 0.f};
        floatx4 acc1 = {0.f, 0.f, 0.f, 0.f};
#pragma unroll
        for (int kstep = 0; kstep < KSTEPS; kstep++) {
            short8_t gf = (kstep & 1) ? g1[kstep >> 1] : g0[kstep >> 1];
            short8_t wA = wl[(kstep * 2 + 0) * 64];
            short8_t wB = wl[(kstep * 2 + 1) * 64];
            acc0 = __builtin_amdgcn_mfma_f32_16x16x32_bf16(wA, gf, acc0, 0, 0, 0);
            acc1 = __builtin_amdgcn_mfma_f32_16x16x32_bf16(wB, gf, acc1, 0, 0, 0);
        }

        if (valid) {
            float4 o0, o1;
            o0.x = acc0[0] + bias0.x; o0.y = acc0[1] + bias0.y;
            o0.z = acc0[2] + bias0.z; o0.w = acc0[3] + bias0.w;
            o1.x = acc1[0] + bias1.x; o1.y = acc1[1] + bias1.y;
            o1.z = acc1[2] + bias1.z; o1.w = acc1[3] + bias1.w;
            o0.x = o0.x > 0.f ? o0.x : 0.f;  o0.y = o0.y > 0.f ? o0.y : 0.f;
            o0.z = o0.z > 0.f ? o0.z : 0.f;  o0.w = o0.w > 0.f ? o0.w : 0.f;
            o1.x = o1.x > 0.f ? o1.x : 0.f;  o1.y = o1.y > 0.f ? o1.y : 0.f;
            o1.z = o1.z > 0.f ? o1.z : 0.f;  o1.w = o1.w > 0.f ? o1.w : 0.f;
            float* op = outb + (size_t)vr * C_OUT;
            *(float4*)(op + quad * 4)      = o0;
            *(float4*)(op + 16 + quad * 4) = o1;
        }
    }
}

extern "C" void kernel_launch(void* const* d_in, const int* in_sizes, int n_in,
                              void* d_out, int out_size, void* d_ws, size_t ws_size,
                              hipStream_t stream) {
    const float* x      = (const float*)d_in[0];
    const int*   spiral = (const int*)d_in[1];
    const int*   up_idx = (const int*)d_in[2];
    const float* up_val = (const float*)d_in[3];
    const float* weight = (const float*)d_in[4];
    const float* bias   = (const float*)d_in[5];
    float* out = (float*)d_out;

    unsigned short* up_ws  = (unsigned short*)d_ws;          // 200000*64 bf16 = 25.6 MB
    unsigned short* w_frag = up_ws + (size_t)ROWS * C_IN;    // + 36864 B

    upsample_kernel<<<G1 + 1, 256, 0, stream>>>(x, up_idx, up_val, weight, up_ws, w_frag);
    gemm_kernel<<<G2, 256, 0, stream>>>(up_ws, spiral, w_frag, bias, out);
}

// Round 2
// 166.445 us; speedup vs baseline: 1.0000x; 1.0000x over previous
//
#include <hip/hip_runtime.h>
#include <hip/hip_bf16.h>

#define B_     4
#define V_IN   12500
#define V_OUT  50000
#define C_IN   64
#define C_OUT  32
#define SPIRAL 9
#define K_NNZ  3
#define ROWS   (B_ * V_OUT)       // 200000
#define KDIM   (SPIRAL * C_IN)    // 576
#define KSTEPS (KDIM / 32)        // 18 (16x16x32 MFMA)
#define WFRAG_ELEMS (KSTEPS * 2 * 64 * 8)  // 18432 bf16 = 36864 B
#define HFRAG_ELEMS (SPIRAL * 2 * 64 * 8)  // 9216 bf16 = 18432 B (one K-half)

#define GROUPS_PER_B (V_OUT / 16) // 3125 16-row groups per batch (k1)
#define G1           2048         // k1 blocks (+1 W-prep); 256 per XCD
#define TILES_PER_B  782          // 781 full 64-row tiles + one 16-row tail (k2)
#define G2           1024         // k2 blocks; 128 per (b,ch) XCD; 4 blocks/CU
#define G3           2048         // combine blocks

typedef __attribute__((ext_vector_type(8))) short short8_t;      // 8 bf16 (4 VGPRs)
typedef __attribute__((ext_vector_type(4))) float floatx4;       // 4 fp32 acc
typedef __attribute__((ext_vector_type(4))) unsigned short u16x4;

__device__ __forceinline__ unsigned short f32_to_bf16(float f) {
    unsigned int u = __float_as_uint(f);
    unsigned int r = u + 0x7fffu + ((u >> 16) & 1u);   // round-to-nearest-even
    return (unsigned short)(r >> 16);
}

// Kernel 1: up[b,v,c] = sum_k x[b,up_idx[v,k],c]*up_val[v,k] -> bf16,
// stored as TWO channel planes: plane[ch][b][v][32], ch = c>>5.
// Each plane per batch = 50000*64B = 3.2 MB -> fits one XCD's 4 MB L2 in k2.
// XCD-swizzled: block i serves batch b=(i&7)>>1. Streaming data (idx/val/up
// writes) is nontemporal so x[b] (3.2 MB) stays L2-resident for the K_NNZ
// random gathers.
// Block G1: rearrange weight (576x32 fp32) into MFMA fragment order (bf16):
//   w_frag[((kstep*2+ntile)*64+lane)*8+j] = W[kstep*32+(lane>>4)*8+j][ntile*16+(lane&15)]
__global__ __launch_bounds__(256) void upsample_kernel(
    const float* __restrict__ x,
    const int* __restrict__ up_idx,
    const float* __restrict__ up_val,
    const float* __restrict__ weight,
    unsigned short* __restrict__ up_planes,
    unsigned short* __restrict__ w_frag)
{
    int tid = threadIdx.x;
    if (blockIdx.x == G1) {
        for (int idx = tid; idx < WFRAG_ELEMS; idx += 256) {
            int j     = idx & 7;
            int lane  = (idx >> 3) & 63;
            int ntile = (idx >> 9) & 1;
            int kstep = idx >> 10;
            int k = kstep * 32 + (lane >> 4) * 8 + j;
            int n = ntile * 16 + (lane & 15);
            w_frag[idx] = f32_to_bf16(weight[k * C_OUT + n]);
        }
        return;
    }
    int xcd = blockIdx.x & 7;
    int b   = xcd >> 1;                     // batch owned by this XCD pair
    int h   = xcd & 1;
    int j   = blockIdx.x >> 3;              // [0, 256)
    int lane16 = tid & 15;                  // 4 channels each
    int sub    = tid >> 4;                  // row within 16-row group
    int half   = lane16 >> 3;               // channel plane (c>=32)
    int c8     = lane16 & 7;                // 4-short chunk within plane row

    const float* xb = x + (size_t)b * V_IN * C_IN;
    unsigned short* plane = up_planes
        + ((size_t)(half * B_ + b)) * V_OUT * 32 + (size_t)c8 * 4;

    for (int gl = h + 2 * j; gl < GROUPS_PER_B; gl += 512) {
        int v = gl * 16 + sub;              // local row within batch b
        const int*   ui = up_idx + v * K_NNZ;
        const float* uv = up_val + v * K_NNZ;
        float a0 = 0.f, a1 = 0.f, a2 = 0.f, a3 = 0.f;
#pragma unroll
        for (int k = 0; k < K_NNZ; k++) {
            int u = __builtin_nontemporal_load(ui + k);
            float val = __builtin_nontemporal_load(uv + k);
            const float4* xp = (const float4*)(xb + (size_t)u * C_IN) + lane16;
            float4 xv = *xp;
            a0 += val * xv.x; a1 += val * xv.y; a2 += val * xv.z; a3 += val * xv.w;
        }
        u16x4 o;
        o[0] = f32_to_bf16(a0); o[1] = f32_to_bf16(a1);
        o[2] = f32_to_bf16(a2); o[3] = f32_to_bf16(a3);
        __builtin_nontemporal_store(o, (u16x4*)(plane + (size_t)v * 32));
    }
}

// Kernel 2: partial GEMM over one K-half. XCD xcd = b*2+ch: batch b,
// channel-half ch. Global kstep = 2s+ch covers spiral slot s, channels
// [ch*32, ch*32+32) == plane ch. Gather footprint per XCD = 3.2 MB
// (L2-resident). ch==1 writes raw partials to out, ch==0 to p0 (ws);
// combine_kernel finishes bias+relu. All wide stores nontemporal so the
// partial stream does not evict the resident gather plane.
__global__ __launch_bounds__(256, 4) void gemm_half_kernel(
    const unsigned short* __restrict__ up_planes,
    const int* __restrict__ spiral,
    const unsigned short* __restrict__ w_frag,
    float* __restrict__ p0,
    float* __restrict__ out)
{
    __shared__ unsigned short w_lds[HFRAG_ELEMS];   // 18432 B

    int tid  = threadIdx.x;
    int wave = tid >> 6;
    int lane = tid & 63;
    int m    = lane & 15;
    int quad = lane >> 4;

    int xcd = blockIdx.x & 7;
    int b   = xcd >> 1;
    int ch  = xcd & 1;
    int j   = blockIdx.x >> 3;              // [0, 128)

    // Stage this half's 18 W fragments (ksteps 2s+ch) into LDS.
    for (int i = tid; i < HFRAG_ELEMS / 8; i += 256) {
        int fl = i >> 6;                    // local fragment 0..17
        int ln = i & 63;
        int s  = fl >> 1;
        int nt = fl & 1;
        int fg = (2 * s + ch) * 2 + nt;     // global fragment index
        ((short8_t*)w_lds)[i] = ((const short8_t*)w_frag)[fg * 64 + ln];
    }
    __syncthreads();

    const short8_t* wl = (const short8_t*)w_lds + lane;  // + f*64

    const unsigned short* upb = up_planes + ((size_t)(ch * B_ + b)) * V_OUT * 32;
    float* dst = (ch ? out : p0) + (size_t)b * V_OUT * C_OUT;

    // Prologue: load spiral indices for first tile.
    int spv[SPIRAL];
    {
        int vr = j * 64 + wave * 16 + m;
        int v  = vr < V_OUT ? vr : 0;
        const int* p = spiral + v * SPIRAL;
#pragma unroll
        for (int s = 0; s < SPIRAL; s++) spv[s] = __builtin_nontemporal_load(p + s);
    }

    for (int tl = j; tl < TILES_PER_B; tl += 128) {
        // Issue all 9 gathers (16B each) for this tile.
        short8_t g[SPIRAL];
#pragma unroll
        for (int s = 0; s < SPIRAL; s++)
            g[s] = *(const short8_t*)(upb + (size_t)spv[s] * 32 + quad * 8);

        // Prefetch next tile's spiral indices (overlaps with gathers/MFMA).
        int tln = tl + 128;
        if (tln < TILES_PER_B) {
            int vr = tln * 64 + wave * 16 + m;
            int v  = vr < V_OUT ? vr : 0;
            const int* p = spiral + v * SPIRAL;
#pragma unroll
            for (int s = 0; s < SPIRAL; s++) spv[s] = __builtin_nontemporal_load(p + s);
        }

        // Force all gathers live (preloaded) before the MFMA chain — R1's
        // regression was the compiler sinking these into the k-loop.
#pragma unroll
        for (int s = 0; s < SPIRAL; s++) asm volatile("" :: "v"(g[s]));

        floatx4 acc0 = {0.f, 0.f, 0.f, 0.f};
        floatx4 acc1 = {0.f, 0.f, 0.f, 0.f};
#pragma unroll
        for (int s = 0; s < SPIRAL; s++) {
            short8_t wA = wl[(2 * s + 0) * 64];
            short8_t wB = wl[(2 * s + 1) * 64];
            acc0 = __builtin_amdgcn_mfma_f32_16x16x32_bf16(wA, g[s], acc0, 0, 0, 0);
            acc1 = __builtin_amdgcn_mfma_f32_16x16x32_bf16(wB, g[s], acc1, 0, 0, 0);
        }

        int vr = tl * 64 + wave * 16 + m;
        if (vr < V_OUT) {
            float* op = dst + (size_t)vr * C_OUT;
            __builtin_nontemporal_store(acc0, (floatx4*)(op + quad * 4));
            __builtin_nontemporal_store(acc1, (floatx4*)(op + 16 + quad * 4));
        }
    }
}

// Kernel 3: out = relu(out + p0 + bias). Pure streaming, nontemporal.
__global__ __launch_bounds__(256) void combine_kernel(
    const float* __restrict__ p0,
    const float* __restrict__ bias,
    float* __restrict__ out)
{
    const size_t total = (size_t)ROWS * (C_OUT / 4);   // 1.6M float4 units
    size_t idx = (size_t)blockIdx.x * 256 + threadIdx.x;
    size_t stride = (size_t)G3 * 256;
    for (size_t i = idx; i < total; i += stride) {
        floatx4 a = __builtin_nontemporal_load((const floatx4*)p0 + i);
        floatx4 c = __builtin_nontemporal_load((const floatx4*)out + i);
        floatx4 bb = *((const floatx4*)bias + (i & 7));
        floatx4 r = a + c + bb;
        r[0] = fmaxf(r[0], 0.f); r[1] = fmaxf(r[1], 0.f);
        r[2] = fmaxf(r[2], 0.f); r[3] = fmaxf(r[3], 0.f);
        __builtin_nontemporal_store(r, (floatx4*)out + i);
    }
}

extern "C" void kernel_launch(void* const* d_in, const int* in_sizes, int n_in,
                              void* d_out, int out_size, void* d_ws, size_t ws_size,
                              hipStream_t stream) {
    const float* x      = (const float*)d_in[0];
    const int*   spiral = (const int*)d_in[1];
    const int*   up_idx = (const int*)d_in[2];
    const float* up_val = (const float*)d_in[3];
    const float* weight = (const float*)d_in[4];
    const float* bias   = (const float*)d_in[5];
    float* out = (float*)d_out;

    // ws layout: planes (25.6 MB) | w_frag (36 KB) | p0 (25.6 MB) = 51.3 MB
    unsigned short* up_ws  = (unsigned short*)d_ws;
    unsigned short* w_frag = up_ws + (size_t)2 * B_ * V_OUT * 32;
    float* p0 = (float*)(w_frag + WFRAG_ELEMS);

    upsample_kernel<<<G1 + 1, 256, 0, stream>>>(x, up_idx, up_val, weight, up_ws, w_frag);
    gemm_half_kernel<<<G2, 256, 0, stream>>>(up_ws, spiral, w_frag, p0, out);
    combine_kernel<<<G3, 256, 0, stream>>>(p0, bias, out);
}